// Round 1
// baseline (596.086 us; speedup 1.0000x reference)
//
#include <hip/hip_runtime.h>
#include <hip/hip_bf16.h>

#define NNODES 100000
#define NEDGES 1600000
#define DIN 128
#define DOUT 128
#define NHEADS 4
#define NEG_SLOPE 0.2f
#define LN_EPS 1e-5f

// ---------------- K1: h = x @ W, plus a_src/a_dst ----------------
// Block: 256 threads. W (128x128 f32 = 64KB) staged in LDS once.
// Per pass: 8 nodes; thread t -> node slot t>>5, 4 channels at (t&31)*4.
#define NODES_PER_BLOCK 64
#define SLOTS 8

__global__ __launch_bounds__(256) void k_gemm(
    const float* __restrict__ x, const float* __restrict__ W,
    const float* __restrict__ att_src, const float* __restrict__ att_dst,
    float* __restrict__ h, float* __restrict__ a_src, float* __restrict__ a_dst) {
  __shared__ float Wl[DIN * DOUT];
  __shared__ float Xl[SLOTS][DIN];
  const int t = threadIdx.x;
  const int base = blockIdx.x * NODES_PER_BLOCK;
  // stage W (coalesced float4)
  for (int i = t; i < DIN * DOUT / 4; i += 256)
    ((float4*)Wl)[i] = ((const float4*)W)[i];

  const int slot = t >> 5;        // 0..7
  const int jb = (t & 31) * 4;    // channel base 0..124

  for (int pass = 0; pass < NODES_PER_BLOCK / SLOTS; ++pass) {
    const int node = base + pass * SLOTS + slot;
    __syncthreads();  // protect Xl from previous pass readers (also fences W on pass 0)
    float4 xv4 = make_float4(0.f, 0.f, 0.f, 0.f);
    if (node < NNODES) xv4 = *(const float4*)&x[(size_t)node * DIN + jb];
    *(float4*)&Xl[slot][jb] = xv4;
    __syncthreads();

    float4 acc = make_float4(0.f, 0.f, 0.f, 0.f);
    for (int k = 0; k < DIN; ++k) {
      float xv = Xl[slot][k];
      float4 w = *(const float4*)&Wl[k * DOUT + jb];
      acc.x += xv * w.x; acc.y += xv * w.y; acc.z += xv * w.z; acc.w += xv * w.w;
    }
    // attention partials: channels jb..jb+3 all belong to head (t&31)>>3
    float as = acc.x * att_src[jb] + acc.y * att_src[jb + 1] +
               acc.z * att_src[jb + 2] + acc.w * att_src[jb + 3];
    float ad = acc.x * att_dst[jb] + acc.y * att_dst[jb + 1] +
               acc.z * att_dst[jb + 2] + acc.w * att_dst[jb + 3];
    for (int off = 1; off < 8; off <<= 1) {
      as += __shfl_xor(as, off);
      ad += __shfl_xor(ad, off);
    }
    if (node < NNODES) {
      *(float4*)&h[(size_t)node * DIN + jb] = acc;
      if ((t & 7) == 0) {
        int head = (t & 31) >> 3;
        a_src[node * NHEADS + head] = as;
        a_dst[node * NHEADS + head] = ad;
      }
    }
  }
}

// ---------------- CSR build by dst ----------------
__global__ void k_hist(const int* __restrict__ ei, int* __restrict__ deg) {
  int e = blockIdx.x * blockDim.x + threadIdx.x;
  if (e < NEDGES) atomicAdd(&deg[ei[NEDGES + e]], 1);
}

__global__ __launch_bounds__(256) void k_blocksum(const int* __restrict__ deg,
                                                  int* __restrict__ bsum) {
  int i = blockIdx.x * 256 + threadIdx.x;
  int v = (i < NNODES) ? deg[i] : 0;
  for (int off = 1; off < 64; off <<= 1) v += __shfl_xor(v, off);
  __shared__ int s[4];
  if ((threadIdx.x & 63) == 0) s[threadIdx.x >> 6] = v;
  __syncthreads();
  if (threadIdx.x == 0) bsum[blockIdx.x] = s[0] + s[1] + s[2] + s[3];
}

__global__ __launch_bounds__(512) void k_scanbsum(int* __restrict__ bsum, int nb,
                                                  int* __restrict__ offsets) {
  __shared__ int s[512];
  int t = threadIdx.x;
  int v = (t < nb) ? bsum[t] : 0;
  s[t] = v;
  __syncthreads();
  for (int off = 1; off < 512; off <<= 1) {
    int a = 0;
    if (t >= off) a = s[t - off];
    __syncthreads();
    s[t] += a;
    __syncthreads();
  }
  int excl = (t == 0) ? 0 : s[t - 1];
  if (t < nb) bsum[t] = excl;
  if (t == 0) offsets[NNODES] = NEDGES;
}

__global__ __launch_bounds__(256) void k_offsets(const int* __restrict__ deg,
                                                 const int* __restrict__ bsum,
                                                 int* __restrict__ offsets,
                                                 int* __restrict__ cursor) {
  __shared__ int s[256];
  int t = threadIdx.x;
  int i = blockIdx.x * 256 + t;
  int d = (i < NNODES) ? deg[i] : 0;
  s[t] = d;
  __syncthreads();
  for (int off = 1; off < 256; off <<= 1) {
    int a = 0;
    if (t >= off) a = s[t - off];
    __syncthreads();
    s[t] += a;
    __syncthreads();
  }
  int excl = s[t] - d + bsum[blockIdx.x];
  if (i < NNODES) { offsets[i] = excl; cursor[i] = excl; }
}

__global__ void k_scatter(const int* __restrict__ ei, int* __restrict__ cursor,
                          int* __restrict__ sorted_src) {
  int e = blockIdx.x * blockDim.x + threadIdx.x;
  if (e < NEDGES) {
    int dst = ei[NEDGES + e];
    int pos = atomicAdd(&cursor[dst], 1);
    sorted_src[pos] = ei[e];
  }
}

// ---------------- K_agg: softmax-weighted aggregate + bias + LN + PReLU + residual
// One block (128 threads) per destination node; thread t owns channel t (head t>>5).
// No max-subtraction: |e| <~ 8 so exp(e) is safe in fp32; alpha = ex/sum(ex).
__global__ __launch_bounds__(128) void k_agg(
    const int* __restrict__ offs, const int* __restrict__ sorted_src,
    const float* __restrict__ h, const float* __restrict__ a_src,
    const float* __restrict__ a_dst, const float* __restrict__ x,
    const float* __restrict__ bias, const float* __restrict__ gamma,
    const float* __restrict__ beta, const float* __restrict__ prelu,
    float* __restrict__ out) {
  const int n = blockIdx.x;
  const int t = threadIdx.x;
  const int head = t >> 5;
  const float adv = a_dst[n * NHEADS + head];
  const int beg = offs[n], end = offs[n + 1];
  float acc = 0.f, ssum = 0.f;
  for (int i = beg; i < end; ++i) {
    int src = sorted_src[i];
    float e = a_src[src * NHEADS + head] + adv;
    e = (e >= 0.f) ? e : NEG_SLOPE * e;
    float ex = __expf(e);
    ssum += ex;
    acc += ex * h[(size_t)src * DIN + t];
  }
  float v = acc / (ssum + 1e-16f) + bias[t];
  // LayerNorm across the 128 channels (2 waves)
  float s1 = v, s2 = v * v;
  for (int off = 1; off < 64; off <<= 1) {
    s1 += __shfl_xor(s1, off);
    s2 += __shfl_xor(s2, off);
  }
  __shared__ float red[4];
  int wv = t >> 6;
  if ((t & 63) == 0) { red[wv] = s1; red[2 + wv] = s2; }
  __syncthreads();
  float ts = red[0] + red[1], tq = red[2] + red[3];
  float mu = ts * (1.f / DOUT);
  float var = tq * (1.f / DOUT) - mu * mu;
  float o = (v - mu) * rsqrtf(var + LN_EPS) * gamma[t] + beta[t];
  float pw = prelu[0];
  o = (o >= 0.f) ? o : pw * o;
  out[(size_t)n * DIN + t] = o + x[(size_t)n * DIN + t];
}

// ---------------- launch ----------------
extern "C" void kernel_launch(void* const* d_in, const int* in_sizes, int n_in,
                              void* d_out, int out_size, void* d_ws, size_t ws_size,
                              hipStream_t stream) {
  const float* x       = (const float*)d_in[0];
  const int*   ei      = (const int*)d_in[1];   // [2,E] int32 (harness converts int64)
  const float* W       = (const float*)d_in[2];
  const float* att_src = (const float*)d_in[3];
  const float* att_dst = (const float*)d_in[4];
  const float* bias    = (const float*)d_in[5];
  const float* gamma   = (const float*)d_in[6];
  const float* beta    = (const float*)d_in[7];
  const float* prelu   = (const float*)d_in[8];
  float* out = (float*)d_out;

  char* ws = (char*)d_ws;
  size_t off = 0;
  auto alloc = [&](size_t bytes) -> void* {
    void* p = ws + off;
    off += (bytes + 255) & ~(size_t)255;
    return p;
  };
  float* h      = (float*)alloc((size_t)NNODES * DIN * 4);
  float* a_src  = (float*)alloc((size_t)NNODES * NHEADS * 4);
  float* a_dst  = (float*)alloc((size_t)NNODES * NHEADS * 4);
  int*   deg    = (int*)alloc((size_t)NNODES * 4);
  int*   offs   = (int*)alloc((size_t)(NNODES + 1) * 4);
  int*   cursor = (int*)alloc((size_t)NNODES * 4);
  int*   ssrc   = (int*)alloc((size_t)NEDGES * 4);
  const int NB = (NNODES + 255) / 256;  // 391
  int*   bsum   = (int*)alloc((size_t)NB * 4);

  hipMemsetAsync(deg, 0, (size_t)NNODES * 4, stream);
  k_gemm<<<(NNODES + NODES_PER_BLOCK - 1) / NODES_PER_BLOCK, 256, 0, stream>>>(
      x, W, att_src, att_dst, h, a_src, a_dst);
  k_hist<<<(NEDGES + 255) / 256, 256, 0, stream>>>(ei, deg);
  k_blocksum<<<NB, 256, 0, stream>>>(deg, bsum);
  k_scanbsum<<<1, 512, 0, stream>>>(bsum, NB, offs);
  k_offsets<<<NB, 256, 0, stream>>>(deg, bsum, offs, cursor);
  k_scatter<<<(NEDGES + 255) / 256, 256, 0, stream>>>(ei, cursor, ssrc);
  k_agg<<<NNODES, 128, 0, stream>>>(offs, ssrc, h, a_src, a_dst, x, bias, gamma,
                                    beta, prelu, out);
}

// Round 2
// 514.072 us; speedup vs baseline: 1.1595x; 1.1595x over previous
//
#include <hip/hip_runtime.h>
#include <hip/hip_bf16.h>

#define NNODES 100000
#define NEDGES 1600000
#define DIN 128
#define DOUT 128
#define NHEADS 4
#define NEG_SLOPE 0.2f
#define LN_EPS 1e-5f

typedef __attribute__((ext_vector_type(8))) short bf16x8;
typedef __attribute__((ext_vector_type(4))) float f32x4;

__device__ inline ushort f2b(float f) {
  union { float f; uint u; } v; v.f = f;
  uint r = v.u + 0x7fff + ((v.u >> 16) & 1);   // RNE
  return (ushort)(r >> 16);
}
__device__ inline float b2f(ushort u) {
  union { uint u; float f; } v; v.u = ((uint)u) << 16;
  return v.f;
}

// ---------------- W transpose + bf16 cast: Wt[n][k] = bf16(W[k][n]) ----------------
__global__ __launch_bounds__(256) void k_wt(const float* __restrict__ W,
                                            ushort* __restrict__ Wt) {
  int t = threadIdx.x;
  int n = t >> 1;
  int kb = (t & 1) * 64;
  for (int i = 0; i < 16; ++i) {
    ushort4 p;
    p.x = f2b(W[(kb + 4 * i + 0) * DOUT + n]);
    p.y = f2b(W[(kb + 4 * i + 1) * DOUT + n]);
    p.z = f2b(W[(kb + 4 * i + 2) * DOUT + n]);
    p.w = f2b(W[(kb + 4 * i + 3) * DOUT + n]);
    *(ushort4*)&Wt[n * DIN + kb + 4 * i] = p;
  }
}

// ---------------- MFMA GEMM: h = bf16(x) @ bf16(W), h stored bf16 ----------------
// 128 rows per block, 4 waves; wave w -> rows w*32..w*32+31, all 128 cols.
#define BM 128
#define LDP 136   // padded LDS row stride (shorts): +16B -> 2-way banks only

__global__ __launch_bounds__(256) void k_gemm(const float* __restrict__ x,
                                              const ushort* __restrict__ Wt,
                                              ushort* __restrict__ h) {
  __shared__ __align__(16) ushort Xs[BM][LDP];
  __shared__ __align__(16) ushort Ws[DOUT][LDP];
  const int t = threadIdx.x;
  const int brow = blockIdx.x * BM;
  {
    const int row = t >> 1, cb = (t & 1) * 64;
    // stage W^T (bf16, already transposed)
    const ushort* src = &Wt[row * DIN + cb];
    for (int i = 0; i < 8; ++i)
      *(bf16x8*)&Ws[row][cb + 8 * i] = *(const bf16x8*)(src + 8 * i);
    // stage x with fp32->bf16 convert
    const int gr = brow + row;
    for (int i = 0; i < 8; ++i) {
      float4 a = make_float4(0.f, 0.f, 0.f, 0.f), b = a;
      if (gr < NNODES) {
        a = *(const float4*)&x[(size_t)gr * DIN + cb + 8 * i];
        b = *(const float4*)&x[(size_t)gr * DIN + cb + 8 * i + 4];
      }
      ushort4 lo, hi;
      lo.x = f2b(a.x); lo.y = f2b(a.y); lo.z = f2b(a.z); lo.w = f2b(a.w);
      hi.x = f2b(b.x); hi.y = f2b(b.y); hi.z = f2b(b.z); hi.w = f2b(b.w);
      *(ushort4*)&Xs[row][cb + 8 * i] = lo;
      *(ushort4*)&Xs[row][cb + 8 * i + 4] = hi;
    }
  }
  __syncthreads();

  const int w = t >> 6, l = t & 63;
  const int lr = l & 15, lg = l >> 4;
  f32x4 acc[2][8];
  for (int mi = 0; mi < 2; ++mi)
    for (int ni = 0; ni < 8; ++ni)
      acc[mi][ni] = (f32x4){0.f, 0.f, 0.f, 0.f};

  for (int k0 = 0; k0 < 4; ++k0) {
    bf16x8 a0 = *(const bf16x8*)&Xs[w * 32 + lr][k0 * 32 + lg * 8];
    bf16x8 a1 = *(const bf16x8*)&Xs[w * 32 + 16 + lr][k0 * 32 + lg * 8];
#pragma unroll
    for (int ni = 0; ni < 8; ++ni) {
      bf16x8 b = *(const bf16x8*)&Ws[ni * 16 + lr][k0 * 32 + lg * 8];
      acc[0][ni] = __builtin_amdgcn_mfma_f32_16x16x32_bf16(a0, b, acc[0][ni], 0, 0, 0);
      acc[1][ni] = __builtin_amdgcn_mfma_f32_16x16x32_bf16(a1, b, acc[1][ni], 0, 0, 0);
    }
  }
  // store h (bf16): D layout col=lane&15, row=(lane>>4)*4+r
#pragma unroll
  for (int mi = 0; mi < 2; ++mi)
#pragma unroll
    for (int ni = 0; ni < 8; ++ni)
#pragma unroll
      for (int r = 0; r < 4; ++r) {
        int row = brow + w * 32 + mi * 16 + lg * 4 + r;
        if (row < NNODES)
          h[(size_t)row * DOUT + ni * 16 + lr] = f2b(acc[mi][ni][r]);
      }
}

// ---------------- per-node attention terms from bf16 h ----------------
__global__ __launch_bounds__(256) void k_att(const ushort* __restrict__ h,
                                             const float* __restrict__ att_src,
                                             const float* __restrict__ att_dst,
                                             float* __restrict__ a_src,
                                             float* __restrict__ a_dst) {
  int gid = blockIdx.x * 256 + threadIdx.x;
  int node = gid >> 2, head = gid & 3;
  if (node >= NNODES) return;
  const ushort* hp = &h[(size_t)node * DOUT + head * 32];
  float s = 0.f, d = 0.f;
#pragma unroll
  for (int i = 0; i < 8; ++i) {
    ushort4 u = *(const ushort4*)(hp + 4 * i);
    float h0 = b2f(u.x), h1 = b2f(u.y), h2 = b2f(u.z), h3 = b2f(u.w);
    const float* as = &att_src[head * 32 + 4 * i];
    const float* ad = &att_dst[head * 32 + 4 * i];
    s += h0 * as[0] + h1 * as[1] + h2 * as[2] + h3 * as[3];
    d += h0 * ad[0] + h1 * ad[1] + h2 * ad[2] + h3 * ad[3];
  }
  a_src[node * NHEADS + head] = s;
  a_dst[node * NHEADS + head] = d;
}

// ---------------- CSR build by dst ----------------
__global__ void k_hist(const int* __restrict__ ei, int* __restrict__ deg) {
  int e = blockIdx.x * blockDim.x + threadIdx.x;
  if (e < NEDGES) atomicAdd(&deg[ei[NEDGES + e]], 1);
}

__global__ __launch_bounds__(256) void k_blocksum(const int* __restrict__ deg,
                                                  int* __restrict__ bsum) {
  int i = blockIdx.x * 256 + threadIdx.x;
  int v = (i < NNODES) ? deg[i] : 0;
  for (int off = 1; off < 64; off <<= 1) v += __shfl_xor(v, off);
  __shared__ int s[4];
  if ((threadIdx.x & 63) == 0) s[threadIdx.x >> 6] = v;
  __syncthreads();
  if (threadIdx.x == 0) bsum[blockIdx.x] = s[0] + s[1] + s[2] + s[3];
}

__global__ __launch_bounds__(512) void k_scanbsum(int* __restrict__ bsum, int nb,
                                                  int* __restrict__ offsets) {
  __shared__ int s[512];
  int t = threadIdx.x;
  int v = (t < nb) ? bsum[t] : 0;
  s[t] = v;
  __syncthreads();
  for (int off = 1; off < 512; off <<= 1) {
    int a = 0;
    if (t >= off) a = s[t - off];
    __syncthreads();
    s[t] += a;
    __syncthreads();
  }
  int excl = (t == 0) ? 0 : s[t - 1];
  if (t < nb) bsum[t] = excl;
  if (t == 0) offsets[NNODES] = NEDGES;
}

__global__ __launch_bounds__(256) void k_offsets(const int* __restrict__ deg,
                                                 const int* __restrict__ bsum,
                                                 int* __restrict__ offsets,
                                                 int* __restrict__ cursor) {
  __shared__ int s[256];
  int t = threadIdx.x;
  int i = blockIdx.x * 256 + t;
  int d = (i < NNODES) ? deg[i] : 0;
  s[t] = d;
  __syncthreads();
  for (int off = 1; off < 256; off <<= 1) {
    int a = 0;
    if (t >= off) a = s[t - off];
    __syncthreads();
    s[t] += a;
    __syncthreads();
  }
  int excl = s[t] - d + bsum[blockIdx.x];
  if (i < NNODES) { offsets[i] = excl; cursor[i] = excl; }
}

__global__ void k_scatter(const int* __restrict__ ei, int* __restrict__ cursor,
                          int* __restrict__ sorted_src) {
  int e = blockIdx.x * blockDim.x + threadIdx.x;
  if (e < NEDGES) {
    int dst = ei[NEDGES + e];
    int pos = atomicAdd(&cursor[dst], 1);
    sorted_src[pos] = ei[e];
  }
}

// ---------------- fused aggregate + bias + LN + PReLU + residual ----------------
// One 64-lane wave per node; lane l owns channels 2l, 2l+1 (head = l>>4).
// No segment-max: |e| <= ~8 so exp(e) is safe in fp32.
__global__ __launch_bounds__(256) void k_agg(
    const int* __restrict__ offs, const int* __restrict__ ssrc,
    const ushort* __restrict__ h, const float* __restrict__ a_src,
    const float* __restrict__ a_dst, const float* __restrict__ x,
    const float* __restrict__ bias, const float* __restrict__ gamma,
    const float* __restrict__ beta, const float* __restrict__ prelu,
    float* __restrict__ out) {
  const int n = blockIdx.x * 4 + (threadIdx.x >> 6);
  const int l = threadIdx.x & 63;
  const int head = l >> 4;
  const float adv = a_dst[n * NHEADS + head];
  const int beg = offs[n], end = offs[n + 1];
  float acc0 = 0.f, acc1 = 0.f, ssum = 0.f;
  for (int i = beg; i < end; ++i) {
    int src = ssrc[i];
    float e = a_src[src * NHEADS + head] + adv;
    e = fmaxf(e, NEG_SLOPE * e);           // leaky_relu
    float ex = __expf(e);
    ssum += ex;
    uint hv = *(const uint*)&h[(size_t)src * DOUT + 2 * l];
    float h0 = __uint_as_float(hv << 16);
    float h1 = __uint_as_float(hv & 0xffff0000u);
    acc0 += ex * h0;
    acc1 += ex * h1;
  }
  float inv = 1.f / (ssum + 1e-16f);
  float v0 = acc0 * inv + bias[2 * l];
  float v1 = acc1 * inv + bias[2 * l + 1];
  float s1 = v0 + v1, s2 = v0 * v0 + v1 * v1;
  for (int off = 1; off < 64; off <<= 1) {
    s1 += __shfl_xor(s1, off);
    s2 += __shfl_xor(s2, off);
  }
  float mu = s1 * (1.f / DOUT);
  float var = s2 * (1.f / DOUT) - mu * mu;
  float rs = rsqrtf(var + LN_EPS);
  float pw = prelu[0];
  float2 xr = *(const float2*)&x[(size_t)n * DIN + 2 * l];
  float o0 = (v0 - mu) * rs * gamma[2 * l] + beta[2 * l];
  o0 = (o0 >= 0.f) ? o0 : pw * o0;
  float o1 = (v1 - mu) * rs * gamma[2 * l + 1] + beta[2 * l + 1];
  o1 = (o1 >= 0.f) ? o1 : pw * o1;
  *(float2*)&out[(size_t)n * DOUT + 2 * l] = make_float2(o0 + xr.x, o1 + xr.y);
}

// ---------------- launch ----------------
extern "C" void kernel_launch(void* const* d_in, const int* in_sizes, int n_in,
                              void* d_out, int out_size, void* d_ws, size_t ws_size,
                              hipStream_t stream) {
  const float* x       = (const float*)d_in[0];
  const int*   ei      = (const int*)d_in[1];
  const float* W       = (const float*)d_in[2];
  const float* att_src = (const float*)d_in[3];
  const float* att_dst = (const float*)d_in[4];
  const float* bias    = (const float*)d_in[5];
  const float* gamma   = (const float*)d_in[6];
  const float* beta    = (const float*)d_in[7];
  const float* prelu   = (const float*)d_in[8];
  float* out = (float*)d_out;

  char* ws = (char*)d_ws;
  size_t off = 0;
  auto alloc = [&](size_t bytes) -> void* {
    void* p = ws + off;
    off += (bytes + 255) & ~(size_t)255;
    return p;
  };
  ushort* h     = (ushort*)alloc((size_t)NNODES * DOUT * 2);
  ushort* Wt    = (ushort*)alloc((size_t)DIN * DOUT * 2);
  float* a_src  = (float*)alloc((size_t)NNODES * NHEADS * 4);
  float* a_dst  = (float*)alloc((size_t)NNODES * NHEADS * 4);
  int*   deg    = (int*)alloc((size_t)NNODES * 4);
  int*   offs   = (int*)alloc((size_t)(NNODES + 1) * 4);
  int*   cursor = (int*)alloc((size_t)NNODES * 4);
  int*   ssrc   = (int*)alloc((size_t)NEDGES * 4);
  const int NB = (NNODES + 255) / 256;  // 391
  int*   bsum   = (int*)alloc((size_t)NB * 4);

  hipMemsetAsync(deg, 0, (size_t)NNODES * 4, stream);
  k_wt<<<1, 256, 0, stream>>>(W, Wt);
  k_gemm<<<(NNODES + BM - 1) / BM, 256, 0, stream>>>(x, Wt, h);
  k_att<<<(NNODES * NHEADS + 255) / 256, 256, 0, stream>>>(h, att_src, att_dst, a_src, a_dst);
  k_hist<<<(NEDGES + 255) / 256, 256, 0, stream>>>(ei, deg);
  k_blocksum<<<NB, 256, 0, stream>>>(deg, bsum);
  k_scanbsum<<<1, 512, 0, stream>>>(bsum, NB, offs);
  k_offsets<<<NB, 256, 0, stream>>>(deg, bsum, offs, cursor);
  k_scatter<<<(NEDGES + 255) / 256, 256, 0, stream>>>(ei, cursor, ssrc);
  k_agg<<<NNODES / 4, 256, 0, stream>>>(offs, ssrc, h, a_src, a_dst, x, bias, gamma,
                                        beta, prelu, out);
}

// Round 3
// 350.084 us; speedup vs baseline: 1.7027x; 1.4684x over previous
//
#include <hip/hip_runtime.h>
#include <hip/hip_bf16.h>

#define NNODES 100000
#define NEDGES 1600000
#define DIN 128
#define DOUT 128
#define NHEADS 4
#define NEG_SLOPE 0.2f
#define LN_EPS 1e-5f

typedef __attribute__((ext_vector_type(8))) short bf16x8;
typedef __attribute__((ext_vector_type(4))) float f32x4;

__device__ inline ushort f2b(float f) {
  union { float f; uint u; } v; v.f = f;
  uint r = v.u + 0x7fff + ((v.u >> 16) & 1);   // RNE
  return (ushort)(r >> 16);
}

#define NBH ((NEDGES + 255) / 256)   // 6250 hist blocks

// ---------------- hist (+rank) fused with W transpose+cast ----------------
// blocks 0..NBH-1: per-edge dst histogram, store rank (old count).
// block NBH: Wt[n][k] = bf16(W[k][n]).
__global__ __launch_bounds__(256) void k_hist_wt(
    const int* __restrict__ ei, int* __restrict__ deg, int* __restrict__ rank,
    const float* __restrict__ W, ushort* __restrict__ Wt) {
  if (blockIdx.x == NBH) {
    int t = threadIdx.x;
    int n = t >> 1;
    int kb = (t & 1) * 64;
    for (int i = 0; i < 16; ++i) {
      ushort4 p;
      p.x = f2b(W[(kb + 4 * i + 0) * DOUT + n]);
      p.y = f2b(W[(kb + 4 * i + 1) * DOUT + n]);
      p.z = f2b(W[(kb + 4 * i + 2) * DOUT + n]);
      p.w = f2b(W[(kb + 4 * i + 3) * DOUT + n]);
      *(ushort4*)&Wt[n * DIN + kb + 4 * i] = p;
    }
    return;
  }
  int e = blockIdx.x * 256 + threadIdx.x;
  if (e < NEDGES) rank[e] = atomicAdd(&deg[ei[NEDGES + e]], 1);
}

// ---------------- MFMA GEMM: h = bf16(x) @ bf16(W), bf16 out; fused a_src/a_dst ----
#define BM 128
#define LDP 136

__global__ __launch_bounds__(256) void k_gemm(
    const float* __restrict__ x, const ushort* __restrict__ Wt,
    const float* __restrict__ att_src, const float* __restrict__ att_dst,
    ushort* __restrict__ h, float* __restrict__ a_src, float* __restrict__ a_dst) {
  __shared__ __align__(16) ushort Xs[BM][LDP];
  __shared__ __align__(16) ushort Ws[DOUT][LDP];
  const int t = threadIdx.x;
  const int brow = blockIdx.x * BM;
  {
    const int row = t >> 1, cb = (t & 1) * 64;
    const ushort* src = &Wt[row * DIN + cb];
    for (int i = 0; i < 8; ++i)
      *(bf16x8*)&Ws[row][cb + 8 * i] = *(const bf16x8*)(src + 8 * i);
    const int gr = brow + row;
    for (int i = 0; i < 8; ++i) {
      float4 a = make_float4(0.f, 0.f, 0.f, 0.f), b = a;
      if (gr < NNODES) {
        a = *(const float4*)&x[(size_t)gr * DIN + cb + 8 * i];
        b = *(const float4*)&x[(size_t)gr * DIN + cb + 8 * i + 4];
      }
      ushort4 lo, hi;
      lo.x = f2b(a.x); lo.y = f2b(a.y); lo.z = f2b(a.z); lo.w = f2b(a.w);
      hi.x = f2b(b.x); hi.y = f2b(b.y); hi.z = f2b(b.z); hi.w = f2b(b.w);
      *(ushort4*)&Xs[row][cb + 8 * i] = lo;
      *(ushort4*)&Xs[row][cb + 8 * i + 4] = hi;
    }
  }
  __syncthreads();

  const int w = t >> 6, l = t & 63;
  const int lr = l & 15, lg = l >> 4;
  f32x4 acc[2][8];
  for (int mi = 0; mi < 2; ++mi)
    for (int ni = 0; ni < 8; ++ni)
      acc[mi][ni] = (f32x4){0.f, 0.f, 0.f, 0.f};

  for (int k0 = 0; k0 < 4; ++k0) {
    bf16x8 a0 = *(const bf16x8*)&Xs[w * 32 + lr][k0 * 32 + lg * 8];
    bf16x8 a1 = *(const bf16x8*)&Xs[w * 32 + 16 + lr][k0 * 32 + lg * 8];
#pragma unroll
    for (int ni = 0; ni < 8; ++ni) {
      bf16x8 b = *(const bf16x8*)&Ws[ni * 16 + lr][k0 * 32 + lg * 8];
      acc[0][ni] = __builtin_amdgcn_mfma_f32_16x16x32_bf16(a0, b, acc[0][ni], 0, 0, 0);
      acc[1][ni] = __builtin_amdgcn_mfma_f32_16x16x32_bf16(a1, b, acc[1][ni], 0, 0, 0);
    }
  }

  // att coefficients for this lane's 8 columns
  float asr[8], adr[8];
#pragma unroll
  for (int ni = 0; ni < 8; ++ni) {
    asr[ni] = att_src[ni * 16 + lr];
    adr[ni] = att_dst[ni * 16 + lr];
  }

  // store h (bf16) + fused per-row attention terms
#pragma unroll
  for (int mi = 0; mi < 2; ++mi) {
#pragma unroll
    for (int r = 0; r < 4; ++r) {
      const int row = brow + w * 32 + mi * 16 + lg * 4 + r;
      float ps[NHEADS] = {0.f, 0.f, 0.f, 0.f};
      float pd[NHEADS] = {0.f, 0.f, 0.f, 0.f};
#pragma unroll
      for (int ni = 0; ni < 8; ++ni) {
        float v = acc[mi][ni][r];
        ps[ni >> 1] += v * asr[ni];
        pd[ni >> 1] += v * adr[ni];
        if (row < NNODES) h[(size_t)row * DOUT + ni * 16 + lr] = f2b(v);
      }
#pragma unroll
      for (int off = 1; off < 16; off <<= 1) {
#pragma unroll
        for (int hh = 0; hh < NHEADS; ++hh) {
          ps[hh] += __shfl_xor(ps[hh], off);
          pd[hh] += __shfl_xor(pd[hh], off);
        }
      }
      if (lr == 0 && row < NNODES) {
        float4 s4 = make_float4(ps[0], ps[1], ps[2], ps[3]);
        float4 d4 = make_float4(pd[0], pd[1], pd[2], pd[3]);
        *(float4*)&a_src[row * NHEADS] = s4;
        *(float4*)&a_dst[row * NHEADS] = d4;
      }
    }
  }
}

// ---------------- CSR offsets (scan) ----------------
__global__ __launch_bounds__(256) void k_blocksum(const int* __restrict__ deg,
                                                  int* __restrict__ bsum) {
  int i = blockIdx.x * 256 + threadIdx.x;
  int v = (i < NNODES) ? deg[i] : 0;
  for (int off = 1; off < 64; off <<= 1) v += __shfl_xor(v, off);
  __shared__ int s[4];
  if ((threadIdx.x & 63) == 0) s[threadIdx.x >> 6] = v;
  __syncthreads();
  if (threadIdx.x == 0) bsum[blockIdx.x] = s[0] + s[1] + s[2] + s[3];
}

__global__ __launch_bounds__(512) void k_scanbsum(int* __restrict__ bsum, int nb,
                                                  int* __restrict__ offsets) {
  __shared__ int s[512];
  int t = threadIdx.x;
  int v = (t < nb) ? bsum[t] : 0;
  s[t] = v;
  __syncthreads();
  for (int off = 1; off < 512; off <<= 1) {
    int a = 0;
    if (t >= off) a = s[t - off];
    __syncthreads();
    s[t] += a;
    __syncthreads();
  }
  int excl = (t == 0) ? 0 : s[t - 1];
  if (t < nb) bsum[t] = excl;
  if (t == 0) offsets[NNODES] = NEDGES;
}

__global__ __launch_bounds__(256) void k_offsets(const int* __restrict__ deg,
                                                 const int* __restrict__ bsum,
                                                 int* __restrict__ offsets) {
  __shared__ int s[256];
  int t = threadIdx.x;
  int i = blockIdx.x * 256 + t;
  int d = (i < NNODES) ? deg[i] : 0;
  s[t] = d;
  __syncthreads();
  for (int off = 1; off < 256; off <<= 1) {
    int a = 0;
    if (t >= off) a = s[t - off];
    __syncthreads();
    s[t] += a;
    __syncthreads();
  }
  int excl = s[t] - d + bsum[blockIdx.x];
  if (i < NNODES) offsets[i] = excl;
}

// scatter with precomputed rank (no atomics)
__global__ void k_scatter(const int* __restrict__ ei, const int* __restrict__ rank,
                          const int* __restrict__ offs, int* __restrict__ ssrc) {
  int e = blockIdx.x * blockDim.x + threadIdx.x;
  if (e < NEDGES) {
    int dst = ei[NEDGES + e];
    ssrc[offs[dst] + rank[e]] = ei[e];
  }
}

// ---------------- fused aggregate + bias + LN + PReLU + residual ----------------
// One 64-lane wave per node; lane l owns channels 2l,2l+1 (head = l>>4).
// Unrolled x4: batch loads for MLP. No segment-max (|e| <~ 8, exp safe).
__global__ __launch_bounds__(256) void k_agg(
    const int* __restrict__ offs, const int* __restrict__ ssrc,
    const ushort* __restrict__ h, const float* __restrict__ a_src,
    const float* __restrict__ a_dst, const float* __restrict__ x,
    const float* __restrict__ bias, const float* __restrict__ gamma,
    const float* __restrict__ beta, const float* __restrict__ prelu,
    float* __restrict__ out) {
  const int n = blockIdx.x * 4 + (threadIdx.x >> 6);
  const int l = threadIdx.x & 63;
  const int head = l >> 4;
  const float adv = a_dst[n * NHEADS + head];
  const int beg = offs[n], end = offs[n + 1];
  float acc0 = 0.f, acc1 = 0.f, ssum = 0.f;

  int i = beg;
  for (; i + 3 < end; i += 4) {
    int s0 = ssrc[i], s1 = ssrc[i + 1], s2 = ssrc[i + 2], s3 = ssrc[i + 3];
    float e0 = a_src[s0 * NHEADS + head];
    float e1 = a_src[s1 * NHEADS + head];
    float e2 = a_src[s2 * NHEADS + head];
    float e3 = a_src[s3 * NHEADS + head];
    uint hv0 = *(const uint*)&h[(size_t)s0 * DOUT + 2 * l];
    uint hv1 = *(const uint*)&h[(size_t)s1 * DOUT + 2 * l];
    uint hv2 = *(const uint*)&h[(size_t)s2 * DOUT + 2 * l];
    uint hv3 = *(const uint*)&h[(size_t)s3 * DOUT + 2 * l];
    e0 += adv; e1 += adv; e2 += adv; e3 += adv;
    e0 = fmaxf(e0, NEG_SLOPE * e0); e1 = fmaxf(e1, NEG_SLOPE * e1);
    e2 = fmaxf(e2, NEG_SLOPE * e2); e3 = fmaxf(e3, NEG_SLOPE * e3);
    float x0 = __expf(e0), x1 = __expf(e1), x2 = __expf(e2), x3 = __expf(e3);
    ssum += (x0 + x1) + (x2 + x3);
    acc0 += x0 * __uint_as_float(hv0 << 16) + x1 * __uint_as_float(hv1 << 16) +
            x2 * __uint_as_float(hv2 << 16) + x3 * __uint_as_float(hv3 << 16);
    acc1 += x0 * __uint_as_float(hv0 & 0xffff0000u) +
            x1 * __uint_as_float(hv1 & 0xffff0000u) +
            x2 * __uint_as_float(hv2 & 0xffff0000u) +
            x3 * __uint_as_float(hv3 & 0xffff0000u);
  }
  for (; i < end; ++i) {
    int src = ssrc[i];
    float e = a_src[src * NHEADS + head] + adv;
    e = fmaxf(e, NEG_SLOPE * e);
    float ex = __expf(e);
    uint hv = *(const uint*)&h[(size_t)src * DOUT + 2 * l];
    ssum += ex;
    acc0 += ex * __uint_as_float(hv << 16);
    acc1 += ex * __uint_as_float(hv & 0xffff0000u);
  }

  float inv = 1.f / (ssum + 1e-16f);
  float v0 = acc0 * inv + bias[2 * l];
  float v1 = acc1 * inv + bias[2 * l + 1];
  float s1 = v0 + v1, s2 = v0 * v0 + v1 * v1;
  for (int off = 1; off < 64; off <<= 1) {
    s1 += __shfl_xor(s1, off);
    s2 += __shfl_xor(s2, off);
  }
  float mu = s1 * (1.f / DOUT);
  float var = s2 * (1.f / DOUT) - mu * mu;
  float rs = rsqrtf(var + LN_EPS);
  float pw = prelu[0];
  float2 xr = *(const float2*)&x[(size_t)n * DIN + 2 * l];
  float o0 = (v0 - mu) * rs * gamma[2 * l] + beta[2 * l];
  o0 = (o0 >= 0.f) ? o0 : pw * o0;
  float o1 = (v1 - mu) * rs * gamma[2 * l + 1] + beta[2 * l + 1];
  o1 = (o1 >= 0.f) ? o1 : pw * o1;
  *(float2*)&out[(size_t)n * DOUT + 2 * l] = make_float2(o0 + xr.x, o1 + xr.y);
}

// ---------------- launch ----------------
extern "C" void kernel_launch(void* const* d_in, const int* in_sizes, int n_in,
                              void* d_out, int out_size, void* d_ws, size_t ws_size,
                              hipStream_t stream) {
  const float* x       = (const float*)d_in[0];
  const int*   ei      = (const int*)d_in[1];
  const float* W       = (const float*)d_in[2];
  const float* att_src = (const float*)d_in[3];
  const float* att_dst = (const float*)d_in[4];
  const float* bias    = (const float*)d_in[5];
  const float* gamma   = (const float*)d_in[6];
  const float* beta    = (const float*)d_in[7];
  const float* prelu   = (const float*)d_in[8];
  float* out = (float*)d_out;

  char* ws = (char*)d_ws;
  size_t off = 0;
  auto alloc = [&](size_t bytes) -> void* {
    void* p = ws + off;
    off += (bytes + 255) & ~(size_t)255;
    return p;
  };
  ushort* h     = (ushort*)alloc((size_t)NNODES * DOUT * 2);
  ushort* Wt    = (ushort*)alloc((size_t)DIN * DOUT * 2);
  float* a_src  = (float*)alloc((size_t)NNODES * NHEADS * 4);
  float* a_dst  = (float*)alloc((size_t)NNODES * NHEADS * 4);
  int*   deg    = (int*)alloc((size_t)NNODES * 4);
  int*   offs   = (int*)alloc((size_t)(NNODES + 1) * 4);
  int*   rank   = (int*)alloc((size_t)NEDGES * 4);
  int*   ssrc   = (int*)alloc((size_t)NEDGES * 4);
  const int NB = (NNODES + 255) / 256;  // 391
  int*   bsum   = (int*)alloc((size_t)NB * 4);

  hipMemsetAsync(deg, 0, (size_t)NNODES * 4, stream);
  k_hist_wt<<<NBH + 1, 256, 0, stream>>>(ei, deg, rank, W, Wt);
  k_gemm<<<(NNODES + BM - 1) / BM, 256, 0, stream>>>(x, Wt, att_src, att_dst, h,
                                                     a_src, a_dst);
  k_blocksum<<<NB, 256, 0, stream>>>(deg, bsum);
  k_scanbsum<<<1, 512, 0, stream>>>(bsum, NB, offs);
  k_offsets<<<NB, 256, 0, stream>>>(deg, bsum, offs);
  k_scatter<<<NBH, 256, 0, stream>>>(ei, rank, offs, ssrc);
  k_agg<<<NNODES / 4, 256, 0, stream>>>(offs, ssrc, h, a_src, a_dst, x, bias, gamma,
                                        beta, prelu, out);
}